// Round 6
// baseline (151992.078 us; speedup 1.0000x reference)
//
#include <hip/hip_runtime.h>
#include <cstdint>

typedef unsigned long long ull;
#define SCOPE __HIP_MEMORY_SCOPE_AGENT

__device__ __forceinline__ ull ald(const ull* p) {
  return __hip_atomic_load(p, __ATOMIC_RELAXED, SCOPE);
}
__device__ __forceinline__ void ast(ull* p, ull v) {
  __hip_atomic_store(p, v, __ATOMIC_RELAXED, SCOPE);
}
__device__ __forceinline__ float vlo(ull v) { return __uint_as_float((unsigned)v); }
__device__ __forceinline__ unsigned thi(ull v) { return (unsigned)(v >> 32); }
__device__ __forceinline__ ull pack(float f, unsigned t) {
  return ((ull)t << 32) | (ull)__float_as_uint(f);
}
__device__ __forceinline__ float sigm(float x) { return 1.f / (1.f + __expf(-x)); }
__device__ __forceinline__ float tanh_(float x) { return 1.f - 2.f / (__expf(2.f * x) + 1.f); }

// ~100-cycle independent FMA burn: keeps VALU busy (DPM clock signal) while
// poll loads are in flight; 4 chains so issue+dep latency ~= 100cy << load ~600cy.
__device__ __forceinline__ float burn(float x) {
  float a = x, b = x + 0.5f, c = x + 1.f, d = x + 2.f;
#pragma unroll
  for (int i = 0; i < 24; ++i) {
    a = fmaf(a, 1.000001f, 1e-30f);
    b = fmaf(b, 1.000001f, 1e-30f);
    c = fmaf(c, 1.000001f, 1e-30f);
    d = fmaf(d, 1.000001f, 1e-30f);
  }
  return (a + b) + (c + d);
}

// ws layout in 8-byte (value,tag) pairs:
//  Y0   ring: 4 slots x 512 @ 0     (h0 == y0 of layer0)
//  H1Y1 ring: 4 slots x 512 @ 2048  (h1 == y1 of layer1; single merged ring)
//  X    ring: 4 slots x 256 @ 4096  (fed-back model input)
#define Y0 0
#define H1 2048
#define XR 4096

// Tag protocol (cell u in [0, 3*len*128)):
//  y0[u]   tag u+1, slot u&3.  L0[u] polls h0[u-1]=y0 ring, tag u, slot (u+3)&3
//  h1y1[u] tag u+1, slot u&3.  L1[u] polls y0[u] tag u+1;  h1[u-1] tag u, slot (u+3)&3
//  x[u]    tag u+1, slot u&3 (init slots 0..2 = embedding rows, tags 1..3;
//          OUT[v] writes x[v+3] tag v+4).  L0[u] polls x[u] tag u+1.
// Merged-ring safety: L1 writing slot u&3 at cell u requires y0[u] ⇐ L0[u]
// ⇐ x[u] ⇐ OUT[u-3] ⇒ OUT consumed y1[u-4] already. OK.
// Matched tag+value travel in ONE 8B atomic store, so a matched chunk is final
// and may be cached across poll rounds (skip-reload). Exact-match tags mean a
// protocol violation hangs rather than silently corrupting.
// NOTE (v4 fix): biases are added AFTER the 64-lane butterfly reduction; v3
// seeded acc with base before reducing, which summed the bias 64x (absmax 1.15).

__global__ void mg_init(ull* __restrict__ ws8, const float* __restrict__ emb,
                        const int* __restrict__ tempo, const int* __restrict__ keysig,
                        const int* __restrict__ lenp) {
  const int tid = blockIdx.x * blockDim.x + threadIdx.x;
  const int n = gridDim.x * blockDim.x;
  for (int i = tid; i < 4096; i += n) ast(ws8 + i, 0ull);
  for (int i = tid; i < 1024; i += n) {
    const int s = i >> 8, j = i & 255;
    ull v = 0ull;
    if (s < 3) {
      const int r = (s == 0) ? tempo[0] : ((s == 1) ? keysig[0] : lenp[0]);
      v = pack(emb[r * 256 + j], (unsigned)(s + 1));
    }
    ast(ws8 + XR + i, v);
  }
}

// Blocks [0,32): layer0.  [32,64): layer1.  [64,72): output projection.
__global__ __launch_bounds__(512, 2) void mg_main(
    ull* __restrict__ ws8,
    const float* __restrict__ Wih0, const float* __restrict__ Whh0,
    const float* __restrict__ bih0, const float* __restrict__ bhh0,
    const float* __restrict__ Wih1, const float* __restrict__ Whh1,
    const float* __restrict__ bih1, const float* __restrict__ bhh1,
    const float* __restrict__ Wp, const float* __restrict__ bp,
    const float* __restrict__ Wv, const float* __restrict__ bv,
    const int* __restrict__ lenp, float* __restrict__ dout) {
  const int bid = blockIdx.x;
  const int tid = threadIdx.x;
  const int wv = tid >> 6;  // wave 0..7
  const int l = tid & 63;   // lane
  const int NT = 3 * lenp[0] * 128;
  ull* y0r = ws8 + Y0;
  ull* h1r = ws8 + H1;
  ull* xr = ws8 + XR;
  float bx = (float)(tid + 1) * 1e-8f;  // burn carrier (loop-carried, not DCE-able)

  if (bid < 32) {
    // ================= layer 0 =================
    // wave owns h0[k], k = 16*bid + 2*wv + {0,1}; 8 gate rows; w[r][j]: j<8 -> Whh0
    // (x h0_prev), j in 8..11 -> Wih0 (x input x).
    const int beta = bid;
    float w[96], base[8];
    float cst0 = 0.f, cst1 = 0.f;
#pragma unroll
    for (int r = 0; r < 8; ++r) {
      const int row = ((r & 3) << 9) + (beta << 4) + (wv << 1) + (r >> 2);
      base[r] = bih0[row] + bhh0[row];
#pragma unroll
      for (int j = 0; j < 12; ++j) {
        const int c = l + (j << 6);
        w[r * 12 + j] = (j < 8) ? Whh0[row * 512 + c] : Wih0[(row << 8) + (c - 512)];
      }
    }
    const int kg = (beta << 4) + (wv << 1);
    for (int u = 0; u < NT; ++u) {
      float acc[8] = {0.f, 0.f, 0.f, 0.f, 0.f, 0.f, 0.f, 0.f};
      // ---- phase X: input x[u] (available ~3 cells early) ----
      {
        const ull* xp = xr + ((u & 3) << 8);
        const unsigned tx = (unsigned)(u + 1);
        ull dx[4];
        bool dn[4] = {false, false, false, false};
        while (true) {
#pragma unroll
          for (int j = 0; j < 4; ++j)
            if (!dn[j]) dx[j] = ald(xp + (j << 6) + l);
          bx = burn(bx);
          bool all = true;
#pragma unroll
          for (int j = 0; j < 4; ++j) {
            if (!dn[j]) dn[j] = __all(thi(dx[j]) == tx);
            all &= dn[j];
          }
          if (all) break;
        }
#pragma unroll
        for (int j = 0; j < 4; ++j) {
          const float hv = vlo(dx[j]);
#pragma unroll
          for (int r = 0; r < 8; ++r) acc[r] = fmaf(w[r * 12 + 8 + j], hv, acc[r]);
        }
      }
      // ---- phase H: h0[u-1] (the critical h-chain hop) ----
      {
        const ull* hp = y0r + (((u + 3) & 3) << 9);
        const unsigned th = (unsigned)u;
        ull d[8];
        bool dn[8] = {false, false, false, false, false, false, false, false};
        while (true) {
#pragma unroll
          for (int j = 0; j < 8; ++j)
            if (!dn[j]) d[j] = ald(hp + (j << 6) + l);
          bx = burn(bx);
          bool all = true;
#pragma unroll
          for (int j = 0; j < 8; ++j) {
            if (!dn[j]) dn[j] = __all(thi(d[j]) == th);
            all &= dn[j];
          }
          if (all) break;
        }
#pragma unroll
        for (int j = 0; j < 8; ++j) {
          const float hv = vlo(d[j]);
#pragma unroll
          for (int r = 0; r < 8; ++r) acc[r] = fmaf(w[r * 12 + j], hv, acc[r]);
        }
      }
#pragma unroll
      for (int r = 0; r < 8; ++r) {
        float s = acc[r];
#pragma unroll
        for (int off = 32; off > 0; off >>= 1) s += __shfl_xor(s, off, 64);
        acc[r] = s + base[r];  // bias added ONCE, after the lane reduction
      }
      float hn0, hn1;
      {
        const float cn = sigm(acc[1]) * cst0 + sigm(acc[0]) * tanh_(acc[2]);
        cst0 = cn;
        hn0 = sigm(acc[3]) * tanh_(cn);
      }
      {
        const float cn = sigm(acc[5]) * cst1 + sigm(acc[4]) * tanh_(acc[6]);
        cst1 = cn;
        hn1 = sigm(acc[7]) * tanh_(cn);
      }
      if (l < 2) ast(y0r + ((u & 3) << 9) + kg + l, pack(l ? hn1 : hn0, (unsigned)(u + 1)));
    }
  } else if (bid < 64) {
    // ================= layer 1 =================
    // w[r][j]: j<8 -> Wih1 (x y0[u]), j in 8..15 -> Whh1 (x h1[u-1]).
    const int beta = bid - 32;
    float w[128], base[8];
    float cst0 = 0.f, cst1 = 0.f;
#pragma unroll
    for (int r = 0; r < 8; ++r) {
      const int row = ((r & 3) << 9) + (beta << 4) + (wv << 1) + (r >> 2);
      base[r] = bih1[row] + bhh1[row];
#pragma unroll
      for (int j = 0; j < 16; ++j) {
        const int c = l + (j << 6);
        w[r * 16 + j] = (j < 8) ? Wih1[row * 512 + c] : Whh1[row * 512 + (c - 512)];
      }
    }
    const int kg = (beta << 4) + (wv << 1);
    for (int u = 0; u < NT; ++u) {
      float acc[8] = {0.f, 0.f, 0.f, 0.f, 0.f, 0.f, 0.f, 0.f};
      // ---- phase A: h1[u-1] (own-layer chain; arrives while L0 computes y0[u]) ----
      {
        const ull* hp = h1r + (((u + 3) & 3) << 9);
        const unsigned th = (unsigned)u;
        ull d[8];
        bool dn[8] = {false, false, false, false, false, false, false, false};
        while (true) {
#pragma unroll
          for (int j = 0; j < 8; ++j)
            if (!dn[j]) d[j] = ald(hp + (j << 6) + l);
          bx = burn(bx);
          bool all = true;
#pragma unroll
          for (int j = 0; j < 8; ++j) {
            if (!dn[j]) dn[j] = __all(thi(d[j]) == th);
            all &= dn[j];
          }
          if (all) break;
        }
#pragma unroll
        for (int j = 0; j < 8; ++j) {
          const float hv = vlo(d[j]);
#pragma unroll
          for (int r = 0; r < 8; ++r) acc[r] = fmaf(w[r * 16 + 8 + j], hv, acc[r]);
        }
      }
      // ---- phase B: y0[u] (fresh from L0 — the cross-layer hop) ----
      {
        const ull* yp = y0r + ((u & 3) << 9);
        const unsigned ty = (unsigned)(u + 1);
        ull d[8];
        bool dn[8] = {false, false, false, false, false, false, false, false};
        while (true) {
#pragma unroll
          for (int j = 0; j < 8; ++j)
            if (!dn[j]) d[j] = ald(yp + (j << 6) + l);
          bx = burn(bx);
          bool all = true;
#pragma unroll
          for (int j = 0; j < 8; ++j) {
            if (!dn[j]) dn[j] = __all(thi(d[j]) == ty);
            all &= dn[j];
          }
          if (all) break;
        }
#pragma unroll
        for (int j = 0; j < 8; ++j) {
          const float hv = vlo(d[j]);
#pragma unroll
          for (int r = 0; r < 8; ++r) acc[r] = fmaf(w[r * 16 + j], hv, acc[r]);
        }
      }
#pragma unroll
      for (int r = 0; r < 8; ++r) {
        float s = acc[r];
#pragma unroll
        for (int off = 32; off > 0; off >>= 1) s += __shfl_xor(s, off, 64);
        acc[r] = s + base[r];  // bias added ONCE, after the lane reduction
      }
      float hn0, hn1;
      {
        const float cn = sigm(acc[1]) * cst0 + sigm(acc[0]) * tanh_(acc[2]);
        cst0 = cn;
        hn0 = sigm(acc[3]) * tanh_(cn);
      }
      {
        const float cn = sigm(acc[5]) * cst1 + sigm(acc[4]) * tanh_(acc[6]);
        cst1 = cn;
        hn1 = sigm(acc[7]) * tanh_(cn);
      }
      if (l < 2)
        ast(h1r + ((u & 3) << 9) + kg + l, pack(l ? hn1 : hn0, (unsigned)(u + 1)));
    }
  } else {
    // ================= output projection =================
    const int b = bid - 64;
    float w[32], bs[4];
#pragma unroll
    for (int r = 0; r < 4; ++r) {
      const int row = (b << 5) + (wv << 2) + r;
      bs[r] = (row < 128) ? bp[row] : bv[row - 128];
#pragma unroll
      for (int j = 0; j < 8; ++j) {
        const int c = l + (j << 6);
        w[r * 8 + j] = (row < 128) ? Wp[(row << 9) + c] : Wv[((row - 128) << 9) + c];
      }
    }
    for (int u = 0; u < NT; ++u) {
      const ull* yp = h1r + ((u & 3) << 9);
      const unsigned ty = (unsigned)(u + 1);
      ull d[8];
      bool dn[8] = {false, false, false, false, false, false, false, false};
      while (true) {
#pragma unroll
        for (int j = 0; j < 8; ++j)
          if (!dn[j]) d[j] = ald(yp + (j << 6) + l);
        bx = burn(bx);
        bool all = true;
#pragma unroll
        for (int j = 0; j < 8; ++j) {
          if (!dn[j]) dn[j] = __all(thi(d[j]) == ty);
          all &= dn[j];
        }
        if (all) break;
      }
      float a0 = 0.f, a1 = 0.f, a2 = 0.f, a3 = 0.f;
#pragma unroll
      for (int j = 0; j < 8; ++j) {
        const float hv = vlo(d[j]);
        a0 = fmaf(w[0 * 8 + j], hv, a0);
        a1 = fmaf(w[1 * 8 + j], hv, a1);
        a2 = fmaf(w[2 * 8 + j], hv, a2);
        a3 = fmaf(w[3 * 8 + j], hv, a3);
      }
#pragma unroll
      for (int off = 32; off > 0; off >>= 1) {
        a0 += __shfl_xor(a0, off, 64);
        a1 += __shfl_xor(a1, off, 64);
        a2 += __shfl_xor(a2, off, 64);
        a3 += __shfl_xor(a3, off, 64);
      }
      if (l < 4) {
        const int row = (b << 5) + (wv << 2) + l;
        const float val = (l == 0) ? a0 + bs[0]
                        : (l == 1) ? a1 + bs[1]
                        : (l == 2) ? a2 + bs[2]
                                   : a3 + bs[3];
        dout[(size_t)u * 256 + row] = val;
        ast(xr + (((u + 3) & 3) << 8) + row, pack(val, (unsigned)(u + 4)));
      }
    }
  }
  // keep the burn chain alive (prevents DCE; costs nothing)
  asm volatile("" ::"v"(bx));
}

extern "C" void kernel_launch(void* const* d_in, const int* in_sizes, int n_in,
                              void* d_out, int out_size, void* d_ws, size_t ws_size,
                              hipStream_t stream) {
  const int* tempo = (const int*)d_in[0];
  const int* keysig = (const int*)d_in[1];
  const int* lenp = (const int*)d_in[2];
  const float* emb = (const float*)d_in[3];
  const float* Wih0 = (const float*)d_in[4];
  const float* Whh0 = (const float*)d_in[5];
  const float* bih0 = (const float*)d_in[6];
  const float* bhh0 = (const float*)d_in[7];
  const float* Wih1 = (const float*)d_in[8];
  const float* Whh1 = (const float*)d_in[9];
  const float* bih1 = (const float*)d_in[10];
  const float* bhh1 = (const float*)d_in[11];
  const float* Wp = (const float*)d_in[12];
  const float* bp = (const float*)d_in[13];
  const float* Wv = (const float*)d_in[14];
  const float* bv = (const float*)d_in[15];
  ull* ws8 = (ull*)d_ws;
  float* out = (float*)d_out;

  mg_init<<<16, 256, 0, stream>>>(ws8, emb, tempo, keysig, lenp);
  mg_main<<<72, 512, 0, stream>>>(ws8, Wih0, Whh0, bih0, bhh0, Wih1, Whh1, bih1, bhh1,
                                  Wp, bp, Wv, bv, lenp, out);
}

// Round 14
// 98366.412 us; speedup vs baseline: 1.5452x; 1.5452x over previous
//
#include <hip/hip_runtime.h>
#include <cstdint>

typedef unsigned long long ull;

// ws layout in 8-byte (value,tag) pairs — ALL traffic at device scope (sc0 sc1):
//  Y0R @ 0    : y0/h0 merged ring, 4 slots x 512  (L0 output; read by L0 peers AND L1)
//  H1R @ 2048 : h1 ring, 4 slots x 512            (L1 recurrent state)
//  XRR @ 4096 : x ring, 4 slots x 256             (fed-back model input, written by fused OUT)
#define Y0R 0
#define H1R 2048
#define XRR 4096

// Tag protocol (cell u in [0, NT)): value+tag travel in ONE aligned 8B store,
// so a matched chunk is final (skip-reload safe). Exact-match tags: protocol
// violations stall (bounded by poll budget) -> absmax fail, never silent corruption.
//  y0[u] tag u+1 slot u&3.  L0[u] polls y0[u-1] tag u (slot (u+3)&3) + x[u] tag u+1.
//  h1[u] tag u+1 slot u&3.  L1[u] polls y0[u] tag u+1 + h1[u-1] tag u.
//  x[v]  tag v+1 slot v&3.  init x[0..2]=emb rows (tags 1..3); OUT[v] (fused in L1
//        iter v+1) writes x[v+3] tag v+4.
// Ring overwrite safety (depth 4), all transitive:
//  - y0 slot u&3 overwritten by L0[u] (kills y0[u-4]): L0[u] <= x[u] <= OUT[u-3]
//    <= L1 iter u-2 => all L1 consumed y0[u-2] (hence y0[u-4]); all L0 passed u-1
//    => consumed y0[u-4] at cell u-3.
//  - h1 slot u&3 overwritten by L1[u]: L1[u] <= h1[u-1] => all L1 passed u-1 =>
//    consumed h1[u-4] at iter u-3 (OUT reads h1 from LDS stage, not the ring).
//  - x slot (u+2)&3 overwritten during L1 iter u (kills x[u-2]): L1 iter u <=
//    y0[u] => all L0 passed cell u => consumed x[u-2] at cell u-2.

__device__ __forceinline__ float vlo(ull v) { return __uint_as_float((unsigned)v); }
__device__ __forceinline__ unsigned thi(ull v) { return (unsigned)(v >> 32); }
__device__ __forceinline__ ull pack(float f, unsigned t) {
  return ((ull)t << 32) | (ull)__float_as_uint(f);
}
__device__ __forceinline__ float sigm(float x) { return 1.f / (1.f + __expf(-x)); }
__device__ __forceinline__ float tanh_(float x) { return 1.f - 2.f / (__expf(2.f * x) + 1.f); }

// device-scope 8B load/store: bypass L1+L2, served at the device coherence point.
__device__ __forceinline__ void ld_cx(ull& d, const ull* p) {
  asm volatile("global_load_dwordx2 %0, %1, off sc0 sc1" : "=v"(d) : "v"(p));
}
__device__ __forceinline__ void st_cx(ull* p, ull v) {
  asm volatile("global_store_dwordx2 %0, %1, off sc0 sc1" ::"v"(p), "v"(v) : "memory");
}
// one wait for all outstanding poll loads; sched_barrier stops hoisting (rule #18)
__device__ __forceinline__ void waitv() {
  asm volatile("s_waitcnt vmcnt(0)" ::: "memory");
  __builtin_amdgcn_sched_barrier(0);
}

// init writes with the SAME sc0 sc1 path the pollers read — no cross-scope or
// cross-kernel visibility assumptions.
__global__ void mg_init(ull* __restrict__ ws8, const float* __restrict__ emb,
                        const int* __restrict__ tempo, const int* __restrict__ keysig,
                        const int* __restrict__ lenp) {
  const int gid = blockIdx.x * blockDim.x + threadIdx.x;
  const int n = gridDim.x * blockDim.x;
  for (int i = gid; i < 4096; i += n) st_cx(ws8 + i, 0ull);  // y0 + h1 rings (tag 0)
  for (int i = gid; i < 1024; i += n) {
    const int s = i >> 8, j = i & 255;
    ull v = 0ull;
    if (s < 3) {
      const int r = (s == 0) ? tempo[0] : ((s == 1) ? keysig[0] : lenp[0]);
      v = pack(emb[r * 256 + j], (unsigned)(s + 1));
    }
    st_cx(ws8 + XRR + i, v);
  }
}

// 128 blocks x 512 threads. Roles from blockIdx (no XCD steering):
//   blocks [0,64)  = layer0 : wave owns y0 element k = beta*8+wv
//   blocks [64,128)= layer1+fused OUT : wave owns h1 element k; waves 0..3 own out row
// Only wave 0 of each block polls (tagged 8B chunks, skip-reload), stages to LDS,
// one __syncthreads per cell; 8 waves consume from LDS.
__global__ __launch_bounds__(512, 2) void mg_main(
    ull* __restrict__ ws8,
    const float* __restrict__ Wih0, const float* __restrict__ Whh0,
    const float* __restrict__ bih0, const float* __restrict__ bhh0,
    const float* __restrict__ Wih1, const float* __restrict__ Whh1,
    const float* __restrict__ bih1, const float* __restrict__ bhh1,
    const float* __restrict__ Wp, const float* __restrict__ bp,
    const float* __restrict__ Wv, const float* __restrict__ bv,
    const int* __restrict__ lenp, float* __restrict__ dout) {
  const int bid = blockIdx.x;
  const int tid = threadIdx.x;
  const int wv = tid >> 6;  // wave 0..7
  const int l = tid & 63;   // lane
  const int NT = 3 * lenp[0] * 128;
  const int role = bid >> 6;   // 0 = L0, 1 = L1(+OUT)
  const int beta = bid & 63;
  ull* y0r = ws8 + Y0R;
  ull* h1r = ws8 + H1R;
  ull* xr = ws8 + XRR;

  __shared__ float hbuf[2][1024];  // double-buffered input stage

  int bud = 4 << 20;  // failed-poll-round budget: livelock -> absmax fail, not timeout

  if (role == 0) {
    // ========== layer 0: wave owns y0 element k; 4 gate rows x 768 cols ==========
    const int k = (beta << 3) + wv;
    float w[48], base[4];
#pragma unroll
    for (int r = 0; r < 4; ++r) {
      const int row = (r << 9) + k;
      base[r] = bih0[row] + bhh0[row];
#pragma unroll
      for (int j = 0; j < 12; ++j)
        w[r * 12 + j] =
            (j < 4) ? Wih0[row * 256 + (j << 6) + l] : Whh0[row * 512 + ((j - 4) << 6) + l];
    }
    float cst = 0.f;
    for (int u = 0; u < NT; ++u) {
      if (wv == 0) {
        // poll x[u] (chunks 0..3) + y0[u-1] (chunks 4..11)
        ull d[12];
        bool dn[12];
#pragma unroll
        for (int j = 0; j < 12; ++j) dn[j] = false;
        const ull* xp = xr + ((u & 3) << 8);
        const ull* hp = y0r + (((u + 3) & 3) << 9);
        const unsigned tx = (unsigned)(u + 1), th = (unsigned)u;
        while (true) {
#pragma unroll
          for (int j = 0; j < 4; ++j)
            if (!dn[j]) ld_cx(d[j], xp + (j << 6) + l);
#pragma unroll
          for (int j = 4; j < 12; ++j)
            if (!dn[j]) ld_cx(d[j], hp + ((j - 4) << 6) + l);
          waitv();
          bool all = true;
#pragma unroll
          for (int j = 0; j < 12; ++j) {
            if (!dn[j]) {
              if (__all(thi(d[j]) == (j < 4 ? tx : th))) {
                dn[j] = true;
                hbuf[u & 1][(j << 6) + l] = vlo(d[j]);
              } else
                all = false;
            }
          }
          if (all || --bud <= 0) break;
        }
      }
      __syncthreads();
      float a0 = 0.f, a1 = 0.f, a2 = 0.f, a3 = 0.f;
#pragma unroll
      for (int j = 0; j < 12; ++j) {
        const float hv = hbuf[u & 1][(j << 6) + l];
        a0 = fmaf(w[0 * 12 + j], hv, a0);
        a1 = fmaf(w[1 * 12 + j], hv, a1);
        a2 = fmaf(w[2 * 12 + j], hv, a2);
        a3 = fmaf(w[3 * 12 + j], hv, a3);
      }
#pragma unroll
      for (int off = 32; off > 0; off >>= 1) {
        a0 += __shfl_xor(a0, off, 64);
        a1 += __shfl_xor(a1, off, 64);
        a2 += __shfl_xor(a2, off, 64);
        a3 += __shfl_xor(a3, off, 64);
      }
      const float cn = sigm(a1 + base[1]) * cst + sigm(a0 + base[0]) * tanh_(a2 + base[2]);
      cst = cn;
      const float hn = sigm(a3 + base[3]) * tanh_(cn);
      if (l == 0) st_cx(y0r + ((u & 3) << 9) + k, pack(hn, (unsigned)(u + 1)));
    }
  } else {
    // ========== layer 1 + fused OUT: wave owns h1 element k ==========
    const int k = (beta << 3) + wv;
    float w[64], base[4];
#pragma unroll
    for (int r = 0; r < 4; ++r) {
      const int row = (r << 9) + k;
      base[r] = bih1[row] + bhh1[row];
#pragma unroll
      for (int j = 0; j < 16; ++j)
        w[r * 16 + j] =
            (j < 8) ? Wih1[row * 512 + (j << 6) + l] : Whh1[row * 512 + ((j - 8) << 6) + l];
    }
    const int orow = (beta << 2) + wv;  // valid for wv<4
    float wo[8], bo = 0.f;
    if (wv < 4) {
      bo = (orow < 128) ? bp[orow] : bv[orow - 128];
#pragma unroll
      for (int j = 0; j < 8; ++j)
        wo[j] = ((orow < 128) ? Wp : Wv)[(orow & 127) * 512 + (j << 6) + l];
    }
    float cst = 0.f;
    for (int u = 0; u < NT; ++u) {
      if (wv == 0) {
        // poll y0[u] (chunks 0..7) + h1[u-1] (chunks 8..15)
        ull d[16];
        bool dn[16];
#pragma unroll
        for (int j = 0; j < 16; ++j) dn[j] = false;
        const ull* yp = y0r + ((u & 3) << 9);
        const ull* hp = h1r + (((u + 3) & 3) << 9);
        const unsigned ty = (unsigned)(u + 1), th = (unsigned)u;
        while (true) {
#pragma unroll
          for (int j = 0; j < 8; ++j)
            if (!dn[j]) ld_cx(d[j], yp + (j << 6) + l);
#pragma unroll
          for (int j = 8; j < 16; ++j)
            if (!dn[j]) ld_cx(d[j], hp + ((j - 8) << 6) + l);
          waitv();
          bool all = true;
#pragma unroll
          for (int j = 0; j < 16; ++j) {
            if (!dn[j]) {
              if (__all(thi(d[j]) == (j < 8 ? ty : th))) {
                dn[j] = true;
                hbuf[u & 1][(j << 6) + l] = vlo(d[j]);
              } else
                all = false;
            }
          }
          if (all || --bud <= 0) break;
        }
      }
      __syncthreads();
      // L1 matvec for element k
      float a0 = 0.f, a1 = 0.f, a2 = 0.f, a3 = 0.f;
#pragma unroll
      for (int j = 0; j < 16; ++j) {
        const float hv = hbuf[u & 1][(j << 6) + l];
        a0 = fmaf(w[0 * 16 + j], hv, a0);
        a1 = fmaf(w[1 * 16 + j], hv, a1);
        a2 = fmaf(w[2 * 16 + j], hv, a2);
        a3 = fmaf(w[3 * 16 + j], hv, a3);
      }
#pragma unroll
      for (int off = 32; off > 0; off >>= 1) {
        a0 += __shfl_xor(a0, off, 64);
        a1 += __shfl_xor(a1, off, 64);
        a2 += __shfl_xor(a2, off, 64);
        a3 += __shfl_xor(a3, off, 64);
      }
      const float cn = sigm(a1 + base[1]) * cst + sigm(a0 + base[0]) * tanh_(a2 + base[2]);
      cst = cn;
      const float hn = sigm(a3 + base[3]) * tanh_(cn);
      if (l == 0) st_cx(h1r + ((u & 3) << 9) + k, pack(hn, (unsigned)(u + 1)));
      // fused OUT[u-1] from the h1[u-1] half of the stage (hbuf[u&1][512..1023])
      if (wv < 4 && u > 0) {
        float a = 0.f;
#pragma unroll
        for (int j = 0; j < 8; ++j) a = fmaf(wo[j], hbuf[u & 1][512 + (j << 6) + l], a);
#pragma unroll
        for (int off = 32; off > 0; off >>= 1) a += __shfl_xor(a, off, 64);
        if (l == 0) {
          const float val = a + bo;
          dout[(size_t)(u - 1) * 256 + orow] = val;
          // x[(u-1)+3] = x[u+2], tag (u-1)+4 = u+3
          st_cx(xr + (((u + 2) & 3) << 8) + orow, pack(val, (unsigned)(u + 3)));
        }
      }
    }
    // epilogue: OUT[NT-1] needs full h1[NT-1]
    if (wv == 0) {
      ull d[8];
      bool dn[8];
#pragma unroll
      for (int j = 0; j < 8; ++j) dn[j] = false;
      const ull* hp = h1r + (((NT + 3) & 3) << 9);
      const unsigned t = (unsigned)NT;
      while (true) {
#pragma unroll
        for (int j = 0; j < 8; ++j)
          if (!dn[j]) ld_cx(d[j], hp + (j << 6) + l);
        waitv();
        bool all = true;
#pragma unroll
        for (int j = 0; j < 8; ++j) {
          if (!dn[j]) {
            if (__all(thi(d[j]) == t)) {
              dn[j] = true;
              hbuf[NT & 1][512 + (j << 6) + l] = vlo(d[j]);
            } else
              all = false;
          }
        }
        if (all || --bud <= 0) break;
      }
    }
    __syncthreads();
    if (wv < 4) {
      float a = 0.f;
#pragma unroll
      for (int j = 0; j < 8; ++j) a = fmaf(wo[j], hbuf[NT & 1][512 + (j << 6) + l], a);
#pragma unroll
      for (int off = 32; off > 0; off >>= 1) a += __shfl_xor(a, off, 64);
      if (l == 0) dout[(size_t)(NT - 1) * 256 + orow] = a + bo;
    }
  }
}

extern "C" void kernel_launch(void* const* d_in, const int* in_sizes, int n_in,
                              void* d_out, int out_size, void* d_ws, size_t ws_size,
                              hipStream_t stream) {
  const int* tempo = (const int*)d_in[0];
  const int* keysig = (const int*)d_in[1];
  const int* lenp = (const int*)d_in[2];
  const float* emb = (const float*)d_in[3];
  const float* Wih0 = (const float*)d_in[4];
  const float* Whh0 = (const float*)d_in[5];
  const float* bih0 = (const float*)d_in[6];
  const float* bhh0 = (const float*)d_in[7];
  const float* Wih1 = (const float*)d_in[8];
  const float* Whh1 = (const float*)d_in[9];
  const float* bih1 = (const float*)d_in[10];
  const float* bhh1 = (const float*)d_in[11];
  const float* Wp = (const float*)d_in[12];
  const float* bp = (const float*)d_in[13];
  const float* Wv = (const float*)d_in[14];
  const float* bv = (const float*)d_in[15];
  ull* ws8 = (ull*)d_ws;
  float* out = (float*)d_out;

  mg_init<<<16, 256, 0, stream>>>(ws8, emb, tempo, keysig, lenp);
  mg_main<<<128, 512, 0, stream>>>(ws8, Wih0, Whh0, bih0, bhh0, Wih1, Whh1, bih1, bhh1,
                                   Wp, bp, Wv, bv, lenp, out);
}